// Round 9
// baseline (361.196 us; speedup 1.0000x reference)
//
#include <hip/hip_runtime.h>
#include <hip/hip_bf16.h>

// SGC: out = (D^-1/2 (A+I) D^-1/2)^3 X W + b
// R9: (a) k_prop dual-edge gather: half-wave h services even/odd edges, lane
//         loads u32 (2 bf16 feats) -> 1 load instr per 2 edges; combine via
//         __shfl_xor(32). ELL reads cached (no nt).
//     (b) k_setup fuses dtype-detect + W/b convert (local probe per block) +
//         gcur zeroing -> 6 dispatches total.
//     (c) k_build zero-inits LDS slab (deterministic ELL tail).

#define NFEAT 256
#define NCLS  64
#define ELLW  64       // slots per node; P(deg>=64) ~ 1e-18 for Binomial(E,1/N)
#define NPB   128      // nodes per bucket (dst >> 7)
#define BCAP  4096     // per-bucket edge capacity (mean ~2048, sigma ~45)
#define PCHUNK 8192    // edges per partition block

typedef __attribute__((ext_vector_type(8))) short bf16x8;
typedef __attribute__((ext_vector_type(4))) float f32x4;
typedef __attribute__((ext_vector_type(4))) int   i32x4;
typedef __attribute__((ext_vector_type(4))) unsigned int u32x4;

__device__ __forceinline__ float bf2f(unsigned int u) {
    return __uint_as_float(u << 16);
}
__device__ __forceinline__ float bf2f_lo(unsigned int u) {
    return __uint_as_float(u << 16);
}
__device__ __forceinline__ float bf2f_hi(unsigned int u) {
    return __uint_as_float(u & 0xffff0000u);
}
__device__ __forceinline__ unsigned short f2bf(float f) {
    unsigned int u = __float_as_uint(f);
    unsigned int r = u + 0x7fffu + ((u >> 16) & 1u);  // RNE
    return (unsigned short)(r >> 16);
}

// ---------- fused setup: block0 edge-dtype detect; block1 float detect +
// ---------- bias convert + gcur zero; blocks 2.. W convert (local probe) ----
__global__ void k_setup(const void* ei, int twoE, int nnodes,
                        const unsigned int* __restrict__ x, int nwords,
                        const void* __restrict__ Wg, const void* __restrict__ Bg,
                        int* flag, int* fflag, int* gcur, int NB,
                        unsigned short* __restrict__ Wt, float* __restrict__ bc) {
    __shared__ int acc;
    const int t = threadIdx.x;
    const int b = blockIdx.x;
    if (t == 0) acc = 0;
    __syncthreads();

    if (b == 0) {
        const long long* p = (const long long*)ei;
        int nchk = 2048;
        if (nchk > twoE / 2) nchk = twoE / 2;
        int bad = 0;
        for (int i = t; i < nchk; i += 256) {
            long long v = p[i];
            if (v < 0 || v >= (long long)nnodes) bad++;
        }
        if (bad) atomicAdd(&acc, bad);
        __syncthreads();
        if (t == 0) *flag = (acc == 0) ? 1 : 0;  // 1 = int64
        return;
    }

    // float dtype probe (local to each block; x is same dtype as W/b)
    int lim = nwords < 4096 ? nwords : 4096;
    int wild = 0;
    for (int i = t; i < lim; i += 256) {
        unsigned int lo = x[i] & 0xffffu;
        unsigned int expf = (lo >> 7) & 0xffu;
        if (expf >= 0x97u) wild++;  // fp32 mantissa noise read as bf16
    }
    if (wild) atomicAdd(&acc, wild);
    __syncthreads();
    const bool isbf = (acc < 8);

    if (b == 1) {
        if (t == 0) *fflag = isbf ? 1 : 0;
        for (int i = t; i < NB; i += 256) gcur[i] = 0;
        if (t < NCLS) {
            bc[t] = isbf ? bf2f(((const unsigned short*)Bg)[t])
                         : ((const float*)Bg)[t];
        }
        return;
    }

    // W -> bf16 transposed [n][k]
    int i = (b - 2) * 256 + t;
    if (i < NFEAT * NCLS) {
        int n = i >> 8, k = i & 255;  // Wt[n][k] = W[k][n]
        Wt[i] = isbf ? ((const unsigned short*)Wg)[k * NCLS + n]
                     : f2bf(((const float*)Wg)[k * NCLS + n]);
    }
}

// ---------- fused: [0, ngemm) = MFMA GEMM blocks, [ngemm, ..) = partition ----------
__launch_bounds__(256)
__global__ void k_fused(const void* __restrict__ Xg,
                        const unsigned short* __restrict__ Wt,  // [n][k] bf16
                        unsigned short* __restrict__ Yb,        // out bf16 [N][64]
                        int N, int NB, const int* __restrict__ fflag,
                        const void* __restrict__ ei, int E, const int* __restrict__ flag,
                        unsigned int* __restrict__ bucket, int* __restrict__ gcur,
                        int ngemm) {
    __shared__ char smem[32768 + 3 * 1600];  // 37.5 KB
    const int t = threadIdx.x;

    if (blockIdx.x >= ngemm) {
        // ---------------- partition path ----------------
        unsigned int* stage = (unsigned int*)smem;       // 8192 entries
        int* hist = (int*)(smem + 32768);                // [400]
        int* base = hist + 400;
        int* rank = base + 400;
        for (int b = t; b < NB; b += 256) { hist[b] = 0; rank[b] = 0; }
        __syncthreads();
        const int bstart = (blockIdx.x - ngemm) * PCHUNK;
        const bool is64 = (*flag != 0);
#pragma unroll
        for (int i = 0; i < PCHUNK / 256; ++i) {
            int e = bstart + i * 256 + t;
            unsigned int v = 0xFFFFFFFFu;  // sentinel (j=511 impossible: NB<=512)
            if (e < E) {
                int ss, dd;
                if (is64) {
                    ss = (int)__builtin_nontemporal_load((const long long*)ei + e);
                    dd = (int)__builtin_nontemporal_load((const long long*)ei + E + e);
                } else {
                    ss = __builtin_nontemporal_load((const int*)ei + e);
                    dd = __builtin_nontemporal_load((const int*)ei + E + e);
                }
                int j = dd >> 7;
                atomicAdd(&hist[j], 1);
                v = ((unsigned int)j << 23) | ((unsigned int)(dd & 127) << 16) |
                    (unsigned int)ss;
            }
            stage[i * 256 + t] = v;
        }
        __syncthreads();
        for (int b = t; b < NB; b += 256) base[b] = atomicAdd(&gcur[b], hist[b]);
        __syncthreads();
#pragma unroll
        for (int i = 0; i < PCHUNK / 256; ++i) {
            unsigned int v = stage[i * 256 + t];
            if (v != 0xFFFFFFFFu) {
                int j = v >> 23;
                int r = atomicAdd(&rank[j], 1);
                int pos = base[j] + r;
                if (pos < BCAP)
                    bucket[(size_t)j * BCAP + pos] = v & 0x7FFFFFu;  // (ld<<16)|s
            }
        }
        return;
    }

    // ---------------- GEMM path ----------------
    unsigned short* Ws = (unsigned short*)smem;  // 32 KB: 8 ks x 4 nt x 64 lanes x 8 bf16
    for (int it = 0; it < 8; ++it) {
        int idx = t + 256 * it;
        int lane_e = idx & 63;
        int nt = (idx >> 6) & 3;
        int ks = idx >> 8;
        int n = nt * 16 + (lane_e & 15);
        int k = ks * 32 + (lane_e >> 4) * 8;
        const unsigned short* srcp = Wt + n * 256 + k;
        ushort4 v0 = *(const ushort4*)srcp;
        ushort4 v1 = *(const ushort4*)(srcp + 4);
        unsigned short* dstp = &Ws[idx * 8];
        *(ushort4*)dstp = v0;
        *(ushort4*)(dstp + 4) = v1;
    }
    __syncthreads();

    const int wv = t >> 6, lane = t & 63;
    const int m = lane & 15, q = lane >> 4;
    const int row = blockIdx.x * 64 + wv * 16 + m;  // A-operand row for this lane
    const bool rowok = row < N;
    const bool isbf = (*fflag != 0);

    f32x4 acc0 = {0.f, 0.f, 0.f, 0.f};
    f32x4 acc1 = {0.f, 0.f, 0.f, 0.f};
    f32x4 acc2 = {0.f, 0.f, 0.f, 0.f};
    f32x4 acc3 = {0.f, 0.f, 0.f, 0.f};

    for (int ks = 0; ks < 8; ++ks) {
        const int kk = ks * 32 + q * 8;
        bf16x8 af = {0, 0, 0, 0, 0, 0, 0, 0};
        if (rowok) {
            if (isbf) {
                const i32x4* xp = (const i32x4*)((const unsigned short*)Xg + (size_t)row * NFEAT + kk);
                i32x4 raw = __builtin_nontemporal_load(xp);
#pragma unroll
                for (int h = 0; h < 4; ++h) {
                    af[2 * h]     = (short)(raw[h] & 0xffff);
                    af[2 * h + 1] = (short)(((unsigned int)raw[h]) >> 16);
                }
            } else {
                const i32x4* xp = (const i32x4*)((const float*)Xg + (size_t)row * NFEAT + kk);
                i32x4 r0 = __builtin_nontemporal_load(xp);
                i32x4 r1 = __builtin_nontemporal_load(xp + 1);
#pragma unroll
                for (int h = 0; h < 4; ++h) {
                    af[h]     = (short)f2bf(__int_as_float(r0[h]));
                    af[h + 4] = (short)f2bf(__int_as_float(r1[h]));
                }
            }
        }
        const unsigned short* wbase = &Ws[(ks * 4) * 512 + lane * 8];
        bf16x8 b0 = *(const bf16x8*)(wbase);
        bf16x8 b1 = *(const bf16x8*)(wbase + 512);
        bf16x8 b2 = *(const bf16x8*)(wbase + 1024);
        bf16x8 b3 = *(const bf16x8*)(wbase + 1536);
        acc0 = __builtin_amdgcn_mfma_f32_16x16x32_bf16(af, b0, acc0, 0, 0, 0);
        acc1 = __builtin_amdgcn_mfma_f32_16x16x32_bf16(af, b1, acc1, 0, 0, 0);
        acc2 = __builtin_amdgcn_mfma_f32_16x16x32_bf16(af, b2, acc2, 0, 0, 0);
        acc3 = __builtin_amdgcn_mfma_f32_16x16x32_bf16(af, b3, acc3, 0, 0, 0);
    }

    // C/D layout: col = lane&15, row = q*4 + reg
    const int rowbase = blockIdx.x * 64 + wv * 16 + q * 4;
#pragma unroll
    for (int i = 0; i < 4; ++i) {
        int gr = rowbase + i;
        if (gr < N) {
            unsigned short* yp = Yb + (size_t)gr * NCLS + m;
            yp[0]  = f2bf(acc0[i]);
            yp[16] = f2bf(acc1[i]);
            yp[32] = f2bf(acc2[i]);
            yp[48] = f2bf(acc3[i]);
        }
    }
}

// ---------- pass 2: one block per bucket; build 128-node ELL slab in LDS,
// ---------- dump ELL + cnt + dinv coalesced. Zero cross-block write sharing. ----------
__launch_bounds__(256)
__global__ void k_build(const unsigned int* __restrict__ bucket,
                        const int* __restrict__ gcur,
                        int* __restrict__ cnt, float* __restrict__ dinv,
                        unsigned short* __restrict__ ellu, int N) {
    __shared__ unsigned short ellb[NPB * ELLW];  // 16 KB
    __shared__ int lcnt[NPB];
    const int t = threadIdx.x;
    const int j = blockIdx.x;
    if (t < NPB) lcnt[t] = 0;
    {
        u32x4* eb4 = (u32x4*)ellb;
        u32x4 z = {0, 0, 0, 0};
        for (int i = t; i < NPB * ELLW / 8; i += 256) eb4[i] = z;
    }
    __syncthreads();
    int total = gcur[j];
    if (total > BCAP) total = BCAP;
    const unsigned int* bb = bucket + (size_t)j * BCAP;
    for (int i = t; i < total; i += 256) {
        unsigned int v = __builtin_nontemporal_load(bb + i);
        int ld = (v >> 16) & 127;
        int s = v & 0xffffu;
        int r = atomicAdd(&lcnt[ld], 1);
        if (r < ELLW) ellb[(ld << 6) + r] = (unsigned short)s;
    }
    __syncthreads();
    const int node0 = j << 7;
    // dump ELL slab (u32x4 = 8 entries), rows 128B each
    u32x4* ellg = (u32x4*)ellu;  // 8 u32x4 per node
    const u32x4* eb = (const u32x4*)ellb;
    for (int i = t; i < NPB * (ELLW / 8); i += 256) {  // 1024 vec4
        int node = node0 + (i >> 3);
        if (node < N) ellg[(size_t)node0 * 8 + i] = eb[i];
    }
    if (t < NPB) {
        int node = node0 + t;
        if (node < N) {
            int c = lcnt[t];
            cnt[node] = c > ELLW ? ELLW : c;
            dinv[node] = rsqrtf((float)(c + 1));  // +1 = self loop
        }
    }
}

// ---------- propagation hop: one wave per node; half-wave h = even/odd edges,
// ---------- lane pair-index l holds features (2l, 2l+1) as u32 ----------
// out[d] = dinv[d] * ( dinv[d]*Y[d] + sum_s dinv[s]*Y[s] )
__launch_bounds__(256)
__global__ void k_prop(const unsigned short* __restrict__ Yin,  // bf16 [N][64]
                       const unsigned short* __restrict__ ellu,
                       const int* __restrict__ cnt, const float* __restrict__ dinv,
                       unsigned short* __restrict__ Ybout,      // bf16, hops 1-2
                       float* __restrict__ outf,                // fp32, last hop
                       const float* __restrict__ bc, int N) {
    int node = blockIdx.x * 4 + (threadIdx.x >> 6);
    if (node >= N) return;
    const int lane = threadIdx.x & 63;
    const int h = lane >> 5;   // half-wave: 0 = even edges, 1 = odd edges
    const int l = lane & 31;   // feature pair index
    const int deg = cnt[node];
    const float dn = dinv[node];
    const unsigned int yself = *(const unsigned int*)(Yin + (size_t)node * NCLS + 2 * l);
    const unsigned short* erow = ellu + (size_t)node * ELLW;
    float a0 = 0.f, a1 = 0.f;
    int e = 0;
    for (; e + 16 <= deg; e += 16) {  // full batches, no guards
        u32x4 ua = *(const u32x4*)(erow + e);
        u32x4 ub = *(const u32x4*)(erow + e + 8);
        int s[16];
#pragma unroll
        for (int i = 0; i < 4; ++i) {
            s[2 * i]     = __builtin_amdgcn_readfirstlane((int)(ua[i] & 0xffffu));
            s[2 * i + 1] = __builtin_amdgcn_readfirstlane((int)(ua[i] >> 16));
            s[2 * i + 8] = __builtin_amdgcn_readfirstlane((int)(ub[i] & 0xffffu));
            s[2 * i + 9] = __builtin_amdgcn_readfirstlane((int)(ub[i] >> 16));
        }
#pragma unroll
        for (int i = 0; i < 8; ++i) {
            int se  = h ? s[2 * i + 1] : s[2 * i];
            float w = h ? dinv[s[2 * i + 1]] : dinv[s[2 * i]];
            unsigned int y = *(const unsigned int*)(Yin + (size_t)se * NCLS + 2 * l);
            a0 = fmaf(w, bf2f_lo(y), a0);
            a1 = fmaf(w, bf2f_hi(y), a1);
        }
    }
    if (e < deg) {  // one guarded tail batch (ELL row is 64 entries; in-bounds)
        u32x4 ua = *(const u32x4*)(erow + e);
        u32x4 ub = *(const u32x4*)(erow + e + 8);
        int s[16];
#pragma unroll
        for (int i = 0; i < 4; ++i) {
            s[2 * i]     = __builtin_amdgcn_readfirstlane((int)(ua[i] & 0xffffu));
            s[2 * i + 1] = __builtin_amdgcn_readfirstlane((int)(ua[i] >> 16));
            s[2 * i + 8] = __builtin_amdgcn_readfirstlane((int)(ub[i] & 0xffffu));
            s[2 * i + 9] = __builtin_amdgcn_readfirstlane((int)(ub[i] >> 16));
        }
#pragma unroll
        for (int i = 0; i < 8; ++i) {
            int i0 = e + 2 * i, i1 = e + 2 * i + 1;   // wave-uniform conds
            float w0 = (i0 < deg) ? dinv[s[2 * i]] : 0.f;
            float w1 = (i1 < deg) ? dinv[s[2 * i + 1]] : 0.f;
            int se  = h ? s[2 * i + 1] : s[2 * i];    // ELL tail is zeroed -> safe
            float w = h ? w1 : w0;
            unsigned int y = *(const unsigned int*)(Yin + (size_t)se * NCLS + 2 * l);
            a0 = fmaf(w, bf2f_lo(y), a0);
            a1 = fmaf(w, bf2f_hi(y), a1);
        }
    }
    // combine the two half-waves (feature pair l lives in lanes l and l+32)
    a0 += __shfl_xor(a0, 32, 64);
    a1 += __shfl_xor(a1, 32, 64);
    float r0 = dn * fmaf(dn, bf2f_lo(yself), a0);
    float r1 = dn * fmaf(dn, bf2f_hi(yself), a1);
    if (h == 0) {
        if (outf) {
            float2 bv = *(const float2*)(bc + 2 * l);
            float2 o = make_float2(r0 + bv.x, r1 + bv.y);
            *(float2*)(outf + (size_t)node * NCLS + 2 * l) = o;
        } else {
            unsigned int pk = (unsigned int)f2bf(r0) | ((unsigned int)f2bf(r1) << 16);
            *(unsigned int*)(Ybout + (size_t)node * NCLS + 2 * l) = pk;
        }
    }
}

extern "C" void kernel_launch(void* const* d_in, const int* in_sizes, int n_in,
                              void* d_out, int out_size, void* d_ws, size_t ws_size,
                              hipStream_t stream) {
    const void* X  = d_in[0];
    const void* EI = d_in[1];
    const void* W  = d_in[2];
    const void* B  = d_in[3];
    float* out = (float*)d_out;

    const int N = in_sizes[0] / NFEAT;  // 50000
    const int twoE = in_sizes[1];       // 1,600,000
    const int E = twoE / 2;             // 800,000
    const int NB = (N + NPB - 1) / NPB; // 391 buckets

    // ---- carve workspace (256B aligned) ----
    char* p = (char*)d_ws;
    auto alloc = [&](size_t bytes) -> char* {
        char* q = p;
        p += (bytes + 255) & ~(size_t)255;
        return q;
    };
    int*   flag   = (int*)alloc(4);
    int*   fflag  = (int*)alloc(4);
    int*   gcur   = (int*)alloc((size_t)NB * 4);
    int*   cnt    = (int*)alloc((size_t)N * 4);
    float* dinv   = (float*)alloc((size_t)N * 4);
    unsigned short* Wt = (unsigned short*)alloc((size_t)NFEAT * NCLS * 2);  // bf16 [n][k]
    float* bc     = (float*)alloc((size_t)NCLS * 4);
    unsigned int* bucket = (unsigned int*)alloc((size_t)NB * BCAP * 4);  // 6.4 MB
    unsigned short* ellu = (unsigned short*)alloc((size_t)N * ELLW * 2); // 6.4 MB
    unsigned short* Y0 = (unsigned short*)alloc((size_t)N * NCLS * 2);   // bf16
    unsigned short* Y1 = (unsigned short*)alloc((size_t)N * NCLS * 2);   // bf16

    k_setup<<<2 + NFEAT * NCLS / 256, 256, 0, stream>>>(
        EI, twoE, N, (const unsigned int*)X, in_sizes[0] / 2,
        W, B, flag, fflag, gcur, NB, Wt, bc);

    const int ngemm = (N + 63) / 64;              // 782
    const int npart = (E + PCHUNK - 1) / PCHUNK;  // 98
    k_fused<<<ngemm + npart, 256, 0, stream>>>(X, Wt, Y0, N, NB, fflag,
                                               EI, E, flag, bucket, gcur, ngemm);

    k_build<<<NB, 256, 0, stream>>>(bucket, gcur, cnt, dinv, ellu, N);

    int nb_p = (N + 3) / 4;
    k_prop<<<nb_p, 256, 0, stream>>>(Y0, ellu, cnt, dinv, Y1, nullptr, bc, N);
    k_prop<<<nb_p, 256, 0, stream>>>(Y1, ellu, cnt, dinv, Y0, nullptr, bc, N);
    k_prop<<<nb_p, 256, 0, stream>>>(Y0, ellu, cnt, dinv, nullptr, out, bc, N);
}

// Round 10
// 235.090 us; speedup vs baseline: 1.5364x; 1.5364x over previous
//
#include <hip/hip_runtime.h>
#include <hip/hip_bf16.h>

// SGC: out = (D^-1/2 (A+I) D^-1/2)^3 X W + b
// R10: Z-formulation + feature-split hops for per-XCD L2 residency.
//   Z = dinv .* Y  ->  Z_{k+1}[d] = dinv_d^2 * (Z_k[d] + sum_s Z_k[s])
//     (pure gather+add per edge: no per-edge weights, no scalar broadcasts,
//      NO cross-lane ops -- R9's __shfl_xor(32) hit an LDS fallback: 16KB LDS
//      + 9M bank conflicts; never split a reduction across the 32-lane line.)
//   Features split into ZA/ZB [N][32] bf16 (3.2 MB each, row = one 64B line);
//   two independent 3-hop pipelines -> random-gather working set fits one
//   XCD's 4 MB L2. ELL reads nontemporal so the stream doesn't evict Z.

#define NFEAT 256
#define NCLS  64
#define ELLW  64       // slots per node; P(deg>=64) ~ 1e-18 for Binomial(E,1/N)
#define NPB   128      // nodes per bucket (dst >> 7)
#define BCAP  4096     // per-bucket edge capacity (mean ~2048, sigma ~45)
#define PCHUNK 8192    // edges per partition block

typedef __attribute__((ext_vector_type(8))) short bf16x8;
typedef __attribute__((ext_vector_type(4))) float f32x4;
typedef __attribute__((ext_vector_type(4))) int   i32x4;
typedef __attribute__((ext_vector_type(4))) unsigned int u32x4;

__device__ __forceinline__ float bf2f(unsigned int u) {
    return __uint_as_float(u << 16);
}
__device__ __forceinline__ float bf2f_hi(unsigned int u) {
    return __uint_as_float(u & 0xffff0000u);
}
__device__ __forceinline__ unsigned short f2bf(float f) {
    unsigned int u = __float_as_uint(f);
    unsigned int r = u + 0x7fffu + ((u >> 16) & 1u);  // RNE
    return (unsigned short)(r >> 16);
}
__device__ __forceinline__ unsigned int pack2bf(float a, float b) {
    return (unsigned int)f2bf(a) | ((unsigned int)f2bf(b) << 16);
}

// ---------- fused setup: block0 edge-dtype detect; block1 float detect +
// ---------- bias convert + gcur zero; blocks 2.. W convert (local probe) ----
__global__ void k_setup(const void* ei, int twoE, int nnodes,
                        const unsigned int* __restrict__ x, int nwords,
                        const void* __restrict__ Wg, const void* __restrict__ Bg,
                        int* flag, int* fflag, int* gcur, int NB,
                        unsigned short* __restrict__ Wt, float* __restrict__ bc) {
    __shared__ int acc;
    const int t = threadIdx.x;
    const int b = blockIdx.x;
    if (t == 0) acc = 0;
    __syncthreads();

    if (b == 0) {
        const long long* p = (const long long*)ei;
        int nchk = 2048;
        if (nchk > twoE / 2) nchk = twoE / 2;
        int bad = 0;
        for (int i = t; i < nchk; i += 256) {
            long long v = p[i];
            if (v < 0 || v >= (long long)nnodes) bad++;
        }
        if (bad) atomicAdd(&acc, bad);
        __syncthreads();
        if (t == 0) *flag = (acc == 0) ? 1 : 0;  // 1 = int64
        return;
    }

    // float dtype probe (local to each block; x is same dtype as W/b)
    int lim = nwords < 4096 ? nwords : 4096;
    int wild = 0;
    for (int i = t; i < lim; i += 256) {
        unsigned int lo = x[i] & 0xffffu;
        unsigned int expf = (lo >> 7) & 0xffu;
        if (expf >= 0x97u) wild++;  // fp32 mantissa noise read as bf16
    }
    if (wild) atomicAdd(&acc, wild);
    __syncthreads();
    const bool isbf = (acc < 8);

    if (b == 1) {
        if (t == 0) *fflag = isbf ? 1 : 0;
        for (int i = t; i < NB; i += 256) gcur[i] = 0;
        if (t < NCLS) {
            bc[t] = isbf ? bf2f(((const unsigned short*)Bg)[t])
                         : ((const float*)Bg)[t];
        }
        return;
    }

    // W -> bf16 transposed [n][k]
    int i = (b - 2) * 256 + t;
    if (i < NFEAT * NCLS) {
        int n = i >> 8, k = i & 255;  // Wt[n][k] = W[k][n]
        Wt[i] = isbf ? ((const unsigned short*)Wg)[k * NCLS + n]
                     : f2bf(((const float*)Wg)[k * NCLS + n]);
    }
}

// ---------- fused: [0, ngemm) = MFMA GEMM blocks, [ngemm, ..) = partition ----------
__launch_bounds__(256)
__global__ void k_fused(const void* __restrict__ Xg,
                        const unsigned short* __restrict__ Wt,  // [n][k] bf16
                        unsigned short* __restrict__ Yb,        // out bf16 [N][64]
                        int N, int NB, const int* __restrict__ fflag,
                        const void* __restrict__ ei, int E, const int* __restrict__ flag,
                        unsigned int* __restrict__ bucket, int* __restrict__ gcur,
                        int ngemm) {
    __shared__ char smem[32768 + 3 * 1600];  // 37.5 KB
    const int t = threadIdx.x;

    if (blockIdx.x >= ngemm) {
        // ---------------- partition path ----------------
        unsigned int* stage = (unsigned int*)smem;       // 8192 entries
        int* hist = (int*)(smem + 32768);                // [400]
        int* base = hist + 400;
        int* rank = base + 400;
        for (int b = t; b < NB; b += 256) { hist[b] = 0; rank[b] = 0; }
        __syncthreads();
        const int bstart = (blockIdx.x - ngemm) * PCHUNK;
        const bool is64 = (*flag != 0);
#pragma unroll
        for (int i = 0; i < PCHUNK / 256; ++i) {
            int e = bstart + i * 256 + t;
            unsigned int v = 0xFFFFFFFFu;  // sentinel
            if (e < E) {
                int ss, dd;
                if (is64) {
                    ss = (int)__builtin_nontemporal_load((const long long*)ei + e);
                    dd = (int)__builtin_nontemporal_load((const long long*)ei + E + e);
                } else {
                    ss = __builtin_nontemporal_load((const int*)ei + e);
                    dd = __builtin_nontemporal_load((const int*)ei + E + e);
                }
                int j = dd >> 7;
                atomicAdd(&hist[j], 1);
                v = ((unsigned int)j << 23) | ((unsigned int)(dd & 127) << 16) |
                    (unsigned int)ss;
            }
            stage[i * 256 + t] = v;
        }
        __syncthreads();
        for (int b = t; b < NB; b += 256) base[b] = atomicAdd(&gcur[b], hist[b]);
        __syncthreads();
#pragma unroll
        for (int i = 0; i < PCHUNK / 256; ++i) {
            unsigned int v = stage[i * 256 + t];
            if (v != 0xFFFFFFFFu) {
                int j = v >> 23;
                int r = atomicAdd(&rank[j], 1);
                int pos = base[j] + r;
                if (pos < BCAP)
                    bucket[(size_t)j * BCAP + pos] = v & 0x7FFFFFu;  // (ld<<16)|s
            }
        }
        return;
    }

    // ---------------- GEMM path ----------------
    unsigned short* Ws = (unsigned short*)smem;  // 32 KB
    for (int it = 0; it < 8; ++it) {
        int idx = t + 256 * it;
        int lane_e = idx & 63;
        int nt = (idx >> 6) & 3;
        int ks = idx >> 8;
        int n = nt * 16 + (lane_e & 15);
        int k = ks * 32 + (lane_e >> 4) * 8;
        const unsigned short* srcp = Wt + n * 256 + k;
        ushort4 v0 = *(const ushort4*)srcp;
        ushort4 v1 = *(const ushort4*)(srcp + 4);
        unsigned short* dstp = &Ws[idx * 8];
        *(ushort4*)dstp = v0;
        *(ushort4*)(dstp + 4) = v1;
    }
    __syncthreads();

    const int wv = t >> 6, lane = t & 63;
    const int m = lane & 15, q = lane >> 4;
    const int row = blockIdx.x * 64 + wv * 16 + m;
    const bool rowok = row < N;
    const bool isbf = (*fflag != 0);

    f32x4 acc0 = {0.f, 0.f, 0.f, 0.f};
    f32x4 acc1 = {0.f, 0.f, 0.f, 0.f};
    f32x4 acc2 = {0.f, 0.f, 0.f, 0.f};
    f32x4 acc3 = {0.f, 0.f, 0.f, 0.f};

    for (int ks = 0; ks < 8; ++ks) {
        const int kk = ks * 32 + q * 8;
        bf16x8 af = {0, 0, 0, 0, 0, 0, 0, 0};
        if (rowok) {
            if (isbf) {
                const i32x4* xp = (const i32x4*)((const unsigned short*)Xg + (size_t)row * NFEAT + kk);
                i32x4 raw = __builtin_nontemporal_load(xp);
#pragma unroll
                for (int h = 0; h < 4; ++h) {
                    af[2 * h]     = (short)(raw[h] & 0xffff);
                    af[2 * h + 1] = (short)(((unsigned int)raw[h]) >> 16);
                }
            } else {
                const i32x4* xp = (const i32x4*)((const float*)Xg + (size_t)row * NFEAT + kk);
                i32x4 r0 = __builtin_nontemporal_load(xp);
                i32x4 r1 = __builtin_nontemporal_load(xp + 1);
#pragma unroll
                for (int h = 0; h < 4; ++h) {
                    af[h]     = (short)f2bf(__int_as_float(r0[h]));
                    af[h + 4] = (short)f2bf(__int_as_float(r1[h]));
                }
            }
        }
        const unsigned short* wbase = &Ws[(ks * 4) * 512 + lane * 8];
        bf16x8 b0 = *(const bf16x8*)(wbase);
        bf16x8 b1 = *(const bf16x8*)(wbase + 512);
        bf16x8 b2 = *(const bf16x8*)(wbase + 1024);
        bf16x8 b3 = *(const bf16x8*)(wbase + 1536);
        acc0 = __builtin_amdgcn_mfma_f32_16x16x32_bf16(af, b0, acc0, 0, 0, 0);
        acc1 = __builtin_amdgcn_mfma_f32_16x16x32_bf16(af, b1, acc1, 0, 0, 0);
        acc2 = __builtin_amdgcn_mfma_f32_16x16x32_bf16(af, b2, acc2, 0, 0, 0);
        acc3 = __builtin_amdgcn_mfma_f32_16x16x32_bf16(af, b3, acc3, 0, 0, 0);
    }

    // C/D layout: col = lane&15, row = q*4 + reg
    const int rowbase = blockIdx.x * 64 + wv * 16 + q * 4;
#pragma unroll
    for (int i = 0; i < 4; ++i) {
        int gr = rowbase + i;
        if (gr < N) {
            unsigned short* yp = Yb + (size_t)gr * NCLS + m;
            yp[0]  = f2bf(acc0[i]);
            yp[16] = f2bf(acc1[i]);
            yp[32] = f2bf(acc2[i]);
            yp[48] = f2bf(acc3[i]);
        }
    }
}

// ---------- pass 2: one block per bucket; build 128-node ELL slab in LDS,
// ---------- dump ELL+cnt+dinv coalesced; split+scale Y0 -> ZA0/ZB0 ----------
__launch_bounds__(256)
__global__ void k_build(const unsigned int* __restrict__ bucket,
                        const int* __restrict__ gcur,
                        int* __restrict__ cnt, float* __restrict__ dinv,
                        unsigned short* __restrict__ ellu,
                        const unsigned short* __restrict__ Yb,  // [N][64] bf16
                        unsigned short* __restrict__ ZA,        // [N][32] bf16
                        unsigned short* __restrict__ ZB,        // [N][32] bf16
                        int N) {
    __shared__ unsigned short ellb[NPB * ELLW];  // 16 KB
    __shared__ int lcnt[NPB];
    __shared__ float sdinv[NPB];
    const int t = threadIdx.x;
    const int j = blockIdx.x;
    if (t < NPB) lcnt[t] = 0;
    {
        u32x4* eb4 = (u32x4*)ellb;
        u32x4 z = {0, 0, 0, 0};
        for (int i = t; i < NPB * ELLW / 8; i += 256) eb4[i] = z;
    }
    __syncthreads();
    int total = gcur[j];
    if (total > BCAP) total = BCAP;
    const unsigned int* bb = bucket + (size_t)j * BCAP;
    for (int i = t; i < total; i += 256) {
        unsigned int v = __builtin_nontemporal_load(bb + i);
        int ld = (v >> 16) & 127;
        int s = v & 0xffffu;
        int r = atomicAdd(&lcnt[ld], 1);
        if (r < ELLW) ellb[(ld << 6) + r] = (unsigned short)s;
    }
    __syncthreads();
    const int node0 = j << 7;
    if (t < NPB) {
        int node = node0 + t;
        int c = lcnt[t];
        float dv = rsqrtf((float)(c + 1));  // +1 = self loop
        sdinv[t] = dv;
        if (node < N) {
            cnt[node] = c > ELLW ? ELLW : c;
            dinv[node] = dv;
        }
    }
    __syncthreads();
    // dump ELL slab (u32x4 = 8 entries), rows 128B each
    u32x4* ellg = (u32x4*)ellu;
    const u32x4* eb = (const u32x4*)ellb;
    for (int i = t; i < NPB * (ELLW / 8); i += 256) {
        int node = node0 + (i >> 3);
        if (node < N) ellg[(size_t)node0 * 8 + i] = eb[i];
    }
    // Z0 = dinv .* Y0, split into halves (u32 = 2 bf16 feats)
    const unsigned int* y32 = (const unsigned int*)Yb;  // [N][32] u32
    unsigned int* za32 = (unsigned int*)ZA;             // [N][16] u32
    unsigned int* zb32 = (unsigned int*)ZB;
    for (int w = t; w < NPB * 16; w += 256) {
        int nl = w >> 4, l2 = w & 15;
        int node = node0 + nl;
        if (node < N) {
            float dv = sdinv[nl];
            unsigned int ya = y32[(size_t)node * 32 + l2];
            unsigned int yb = y32[(size_t)node * 32 + 16 + l2];
            za32[(size_t)node * 16 + l2] = pack2bf(dv * bf2f(ya), dv * bf2f_hi(ya));
            zb32[(size_t)node * 16 + l2] = pack2bf(dv * bf2f(yb), dv * bf2f_hi(yb));
        }
    }
}

// ---------- hop on one feature half: 8 nodes/block, 32 lanes per node ----------
// Zout[d] = dinv_d^2 * (Zin[d] + sum_s Zin[s]);  last hop writes fp32 + bias.
__launch_bounds__(256)
__global__ void k_hop(const unsigned short* __restrict__ Zin,  // [N][32] bf16
                      const unsigned short* __restrict__ ellu,
                      const int* __restrict__ cnt, const float* __restrict__ dinv,
                      unsigned short* __restrict__ Zout,       // hops 1-2
                      float* __restrict__ outf,                // last hop [N][64]
                      const float* __restrict__ bc, int coloff, int N) {
    int node = blockIdx.x * 8 + (threadIdx.x >> 5);
    if (node >= N) return;
    const int l = threadIdx.x & 31;
    const int deg = cnt[node];
    const float dn = dinv[node];
    float acc = bf2f(Zin[(size_t)node * 32 + l]);  // self (Z[d])
    const unsigned short* erow = ellu + (size_t)node * ELLW;
    int e = 0;
    for (; e + 8 <= deg; e += 8) {
        u32x4 u = __builtin_nontemporal_load((const u32x4*)(erow + e));
#pragma unroll
        for (int i = 0; i < 4; ++i) {
            int s0 = (int)(u[i] & 0xffffu);
            int s1 = (int)(u[i] >> 16);
            acc += bf2f(Zin[(size_t)s0 * 32 + l]);
            acc += bf2f(Zin[(size_t)s1 * 32 + l]);
        }
    }
    if (e < deg) {  // tail batch; ELL tail zeroed -> s=0 reads are safe
        u32x4 u = __builtin_nontemporal_load((const u32x4*)(erow + e));
#pragma unroll
        for (int i = 0; i < 4; ++i) {
            int s0 = (int)(u[i] & 0xffffu);
            int s1 = (int)(u[i] >> 16);
            float z0 = bf2f(Zin[(size_t)s0 * 32 + l]);
            float z1 = bf2f(Zin[(size_t)s1 * 32 + l]);
            acc += (e + 2 * i < deg) ? z0 : 0.f;
            acc += (e + 2 * i + 1 < deg) ? z1 : 0.f;
        }
    }
    if (outf) {
        outf[(size_t)node * NCLS + coloff + l] = dn * acc + bc[coloff + l];
    } else {
        Zout[(size_t)node * 32 + l] = f2bf(dn * dn * acc);
    }
}

extern "C" void kernel_launch(void* const* d_in, const int* in_sizes, int n_in,
                              void* d_out, int out_size, void* d_ws, size_t ws_size,
                              hipStream_t stream) {
    const void* X  = d_in[0];
    const void* EI = d_in[1];
    const void* W  = d_in[2];
    const void* B  = d_in[3];
    float* out = (float*)d_out;

    const int N = in_sizes[0] / NFEAT;  // 50000
    const int twoE = in_sizes[1];       // 1,600,000
    const int E = twoE / 2;             // 800,000
    const int NB = (N + NPB - 1) / NPB; // 391 buckets

    // ---- carve workspace (256B aligned) ----
    char* p = (char*)d_ws;
    auto alloc = [&](size_t bytes) -> char* {
        char* q = p;
        p += (bytes + 255) & ~(size_t)255;
        return q;
    };
    int*   flag   = (int*)alloc(4);
    int*   fflag  = (int*)alloc(4);
    int*   gcur   = (int*)alloc((size_t)NB * 4);
    int*   cnt    = (int*)alloc((size_t)N * 4);
    float* dinv   = (float*)alloc((size_t)N * 4);
    unsigned short* Wt = (unsigned short*)alloc((size_t)NFEAT * NCLS * 2);
    float* bc     = (float*)alloc((size_t)NCLS * 4);
    unsigned int* bucket = (unsigned int*)alloc((size_t)NB * BCAP * 4);   // 6.4 MB
    unsigned short* ellu = (unsigned short*)alloc((size_t)N * ELLW * 2);  // 6.4 MB
    unsigned short* Y0  = (unsigned short*)alloc((size_t)N * NCLS * 2);   // 6.4 MB
    unsigned short* ZA0 = (unsigned short*)alloc((size_t)N * 32 * 2);     // 3.2 MB
    unsigned short* ZA1 = (unsigned short*)alloc((size_t)N * 32 * 2);
    unsigned short* ZB0 = (unsigned short*)alloc((size_t)N * 32 * 2);
    unsigned short* ZB1 = (unsigned short*)alloc((size_t)N * 32 * 2);

    k_setup<<<2 + NFEAT * NCLS / 256, 256, 0, stream>>>(
        EI, twoE, N, (const unsigned int*)X, in_sizes[0] / 2,
        W, B, flag, fflag, gcur, NB, Wt, bc);

    const int ngemm = (N + 63) / 64;              // 782
    const int npart = (E + PCHUNK - 1) / PCHUNK;  // 98
    k_fused<<<ngemm + npart, 256, 0, stream>>>(X, Wt, Y0, N, NB, fflag,
                                               EI, E, flag, bucket, gcur, ngemm);

    k_build<<<NB, 256, 0, stream>>>(bucket, gcur, cnt, dinv, ellu, Y0, ZA0, ZB0, N);

    const int nb_h = (N + 7) / 8;  // 6250
    // half A: feats 0-31
    k_hop<<<nb_h, 256, 0, stream>>>(ZA0, ellu, cnt, dinv, ZA1, nullptr, bc, 0, N);
    k_hop<<<nb_h, 256, 0, stream>>>(ZA1, ellu, cnt, dinv, ZA0, nullptr, bc, 0, N);
    k_hop<<<nb_h, 256, 0, stream>>>(ZA0, ellu, cnt, dinv, nullptr, out, bc, 0, N);
    // half B: feats 32-63
    k_hop<<<nb_h, 256, 0, stream>>>(ZB0, ellu, cnt, dinv, ZB1, nullptr, bc, 32, N);
    k_hop<<<nb_h, 256, 0, stream>>>(ZB1, ellu, cnt, dinv, ZB0, nullptr, bc, 32, N);
    k_hop<<<nb_h, 256, 0, stream>>>(ZB0, ellu, cnt, dinv, nullptr, out, bc, 32, N);
}

// Round 11
// 186.218 us; speedup vs baseline: 1.9396x; 1.2624x over previous
//
#include <hip/hip_runtime.h>
#include <hip/hip_bf16.h>

// SGC: out = (D^-1/2 (A+I) D^-1/2)^3 X W + b
// R11: Z-formulation, single full-width hop pipeline.
//   Z = dinv .* Y;  Z' = dinv^2 (Z[d] + sum_s Z[s]);  out = dinv*(Z+sum)+b.
//   Hop: 32-lane node-groups on [N][64] bf16 Z (128B rows); lane loads u32
//   (2 feats) -> 1 load instr per edge per 2 nodes; 4+4 acc chains; no
//   per-edge weights, no readfirstlane, NO cross-lane ops (R9 lesson:
//   __shfl across the 32-lane line falls back to LDS = 9M bank conflicts).
//   ELL cached (re-read 3x, fits L2); build pipeline unchanged from R7/R10.

#define NFEAT 256
#define NCLS  64
#define ELLW  64       // slots per node; P(deg>=64) ~ 1e-18 for Binomial(E,1/N)
#define NPB   128      // nodes per bucket (dst >> 7)
#define BCAP  4096     // per-bucket edge capacity (mean ~2048, sigma ~45)
#define PCHUNK 8192    // edges per partition block

typedef __attribute__((ext_vector_type(8))) short bf16x8;
typedef __attribute__((ext_vector_type(4))) float f32x4;
typedef __attribute__((ext_vector_type(4))) int   i32x4;
typedef __attribute__((ext_vector_type(4))) unsigned int u32x4;

__device__ __forceinline__ float bf2f(unsigned int u) {
    return __uint_as_float(u << 16);
}
__device__ __forceinline__ float bf2f_hi(unsigned int u) {
    return __uint_as_float(u & 0xffff0000u);
}
__device__ __forceinline__ unsigned short f2bf(float f) {
    unsigned int u = __float_as_uint(f);
    unsigned int r = u + 0x7fffu + ((u >> 16) & 1u);  // RNE
    return (unsigned short)(r >> 16);
}
__device__ __forceinline__ unsigned int pack2bf(float a, float b) {
    return (unsigned int)f2bf(a) | ((unsigned int)f2bf(b) << 16);
}

// ---------- fused setup: block0 edge-dtype detect; block1 float detect +
// ---------- bias convert + gcur zero; blocks 2.. W convert (local probe) ----
__global__ void k_setup(const void* ei, int twoE, int nnodes,
                        const unsigned int* __restrict__ x, int nwords,
                        const void* __restrict__ Wg, const void* __restrict__ Bg,
                        int* flag, int* fflag, int* gcur, int NB,
                        unsigned short* __restrict__ Wt, float* __restrict__ bc) {
    __shared__ int acc;
    const int t = threadIdx.x;
    const int b = blockIdx.x;
    if (t == 0) acc = 0;
    __syncthreads();

    if (b == 0) {
        const long long* p = (const long long*)ei;
        int nchk = 2048;
        if (nchk > twoE / 2) nchk = twoE / 2;
        int bad = 0;
        for (int i = t; i < nchk; i += 256) {
            long long v = p[i];
            if (v < 0 || v >= (long long)nnodes) bad++;
        }
        if (bad) atomicAdd(&acc, bad);
        __syncthreads();
        if (t == 0) *flag = (acc == 0) ? 1 : 0;  // 1 = int64
        return;
    }

    // float dtype probe (local to each block; x is same dtype as W/b)
    int lim = nwords < 4096 ? nwords : 4096;
    int wild = 0;
    for (int i = t; i < lim; i += 256) {
        unsigned int lo = x[i] & 0xffffu;
        unsigned int expf = (lo >> 7) & 0xffu;
        if (expf >= 0x97u) wild++;  // fp32 mantissa noise read as bf16
    }
    if (wild) atomicAdd(&acc, wild);
    __syncthreads();
    const bool isbf = (acc < 8);

    if (b == 1) {
        if (t == 0) *fflag = isbf ? 1 : 0;
        for (int i = t; i < NB; i += 256) gcur[i] = 0;
        if (t < NCLS) {
            bc[t] = isbf ? bf2f(((const unsigned short*)Bg)[t])
                         : ((const float*)Bg)[t];
        }
        return;
    }

    // W -> bf16 transposed [n][k]
    int i = (b - 2) * 256 + t;
    if (i < NFEAT * NCLS) {
        int n = i >> 8, k = i & 255;  // Wt[n][k] = W[k][n]
        Wt[i] = isbf ? ((const unsigned short*)Wg)[k * NCLS + n]
                     : f2bf(((const float*)Wg)[k * NCLS + n]);
    }
}

// ---------- fused: [0, ngemm) = MFMA GEMM blocks, [ngemm, ..) = partition ----------
__launch_bounds__(256)
__global__ void k_fused(const void* __restrict__ Xg,
                        const unsigned short* __restrict__ Wt,  // [n][k] bf16
                        unsigned short* __restrict__ Yb,        // out bf16 [N][64]
                        int N, int NB, const int* __restrict__ fflag,
                        const void* __restrict__ ei, int E, const int* __restrict__ flag,
                        unsigned int* __restrict__ bucket, int* __restrict__ gcur,
                        int ngemm) {
    __shared__ char smem[32768 + 3 * 1600];  // 37.5 KB
    const int t = threadIdx.x;

    if (blockIdx.x >= ngemm) {
        // ---------------- partition path ----------------
        unsigned int* stage = (unsigned int*)smem;       // 8192 entries
        int* hist = (int*)(smem + 32768);                // [400]
        int* base = hist + 400;
        int* rank = base + 400;
        for (int b = t; b < NB; b += 256) { hist[b] = 0; rank[b] = 0; }
        __syncthreads();
        const int bstart = (blockIdx.x - ngemm) * PCHUNK;
        const bool is64 = (*flag != 0);
#pragma unroll
        for (int i = 0; i < PCHUNK / 256; ++i) {
            int e = bstart + i * 256 + t;
            unsigned int v = 0xFFFFFFFFu;  // sentinel
            if (e < E) {
                int ss, dd;
                if (is64) {
                    ss = (int)__builtin_nontemporal_load((const long long*)ei + e);
                    dd = (int)__builtin_nontemporal_load((const long long*)ei + E + e);
                } else {
                    ss = __builtin_nontemporal_load((const int*)ei + e);
                    dd = __builtin_nontemporal_load((const int*)ei + E + e);
                }
                int j = dd >> 7;
                atomicAdd(&hist[j], 1);
                v = ((unsigned int)j << 23) | ((unsigned int)(dd & 127) << 16) |
                    (unsigned int)ss;
            }
            stage[i * 256 + t] = v;
        }
        __syncthreads();
        for (int b = t; b < NB; b += 256) base[b] = atomicAdd(&gcur[b], hist[b]);
        __syncthreads();
#pragma unroll
        for (int i = 0; i < PCHUNK / 256; ++i) {
            unsigned int v = stage[i * 256 + t];
            if (v != 0xFFFFFFFFu) {
                int j = v >> 23;
                int r = atomicAdd(&rank[j], 1);
                int pos = base[j] + r;
                if (pos < BCAP)
                    bucket[(size_t)j * BCAP + pos] = v & 0x7FFFFFu;  // (ld<<16)|s
            }
        }
        return;
    }

    // ---------------- GEMM path ----------------
    unsigned short* Ws = (unsigned short*)smem;  // 32 KB
    for (int it = 0; it < 8; ++it) {
        int idx = t + 256 * it;
        int lane_e = idx & 63;
        int nt = (idx >> 6) & 3;
        int ks = idx >> 8;
        int n = nt * 16 + (lane_e & 15);
        int k = ks * 32 + (lane_e >> 4) * 8;
        const unsigned short* srcp = Wt + n * 256 + k;
        ushort4 v0 = *(const ushort4*)srcp;
        ushort4 v1 = *(const ushort4*)(srcp + 4);
        unsigned short* dstp = &Ws[idx * 8];
        *(ushort4*)dstp = v0;
        *(ushort4*)(dstp + 4) = v1;
    }
    __syncthreads();

    const int wv = t >> 6, lane = t & 63;
    const int m = lane & 15, q = lane >> 4;
    const int row = blockIdx.x * 64 + wv * 16 + m;
    const bool rowok = row < N;
    const bool isbf = (*fflag != 0);

    f32x4 acc0 = {0.f, 0.f, 0.f, 0.f};
    f32x4 acc1 = {0.f, 0.f, 0.f, 0.f};
    f32x4 acc2 = {0.f, 0.f, 0.f, 0.f};
    f32x4 acc3 = {0.f, 0.f, 0.f, 0.f};

    for (int ks = 0; ks < 8; ++ks) {
        const int kk = ks * 32 + q * 8;
        bf16x8 af = {0, 0, 0, 0, 0, 0, 0, 0};
        if (rowok) {
            if (isbf) {
                const i32x4* xp = (const i32x4*)((const unsigned short*)Xg + (size_t)row * NFEAT + kk);
                i32x4 raw = __builtin_nontemporal_load(xp);
#pragma unroll
                for (int h = 0; h < 4; ++h) {
                    af[2 * h]     = (short)(raw[h] & 0xffff);
                    af[2 * h + 1] = (short)(((unsigned int)raw[h]) >> 16);
                }
            } else {
                const i32x4* xp = (const i32x4*)((const float*)Xg + (size_t)row * NFEAT + kk);
                i32x4 r0 = __builtin_nontemporal_load(xp);
                i32x4 r1 = __builtin_nontemporal_load(xp + 1);
#pragma unroll
                for (int h = 0; h < 4; ++h) {
                    af[h]     = (short)f2bf(__int_as_float(r0[h]));
                    af[h + 4] = (short)f2bf(__int_as_float(r1[h]));
                }
            }
        }
        const unsigned short* wbase = &Ws[(ks * 4) * 512 + lane * 8];
        bf16x8 b0 = *(const bf16x8*)(wbase);
        bf16x8 b1 = *(const bf16x8*)(wbase + 512);
        bf16x8 b2 = *(const bf16x8*)(wbase + 1024);
        bf16x8 b3 = *(const bf16x8*)(wbase + 1536);
        acc0 = __builtin_amdgcn_mfma_f32_16x16x32_bf16(af, b0, acc0, 0, 0, 0);
        acc1 = __builtin_amdgcn_mfma_f32_16x16x32_bf16(af, b1, acc1, 0, 0, 0);
        acc2 = __builtin_amdgcn_mfma_f32_16x16x32_bf16(af, b2, acc2, 0, 0, 0);
        acc3 = __builtin_amdgcn_mfma_f32_16x16x32_bf16(af, b3, acc3, 0, 0, 0);
    }

    // C/D layout: col = lane&15, row = q*4 + reg
    const int rowbase = blockIdx.x * 64 + wv * 16 + q * 4;
#pragma unroll
    for (int i = 0; i < 4; ++i) {
        int gr = rowbase + i;
        if (gr < N) {
            unsigned short* yp = Yb + (size_t)gr * NCLS + m;
            yp[0]  = f2bf(acc0[i]);
            yp[16] = f2bf(acc1[i]);
            yp[32] = f2bf(acc2[i]);
            yp[48] = f2bf(acc3[i]);
        }
    }
}

// ---------- pass 2: one block per bucket; build 128-node ELL slab in LDS,
// ---------- dump ELL+cnt+dinv coalesced; Z = dinv .* Y (bf16 [N][64]) ----------
__launch_bounds__(256)
__global__ void k_build(const unsigned int* __restrict__ bucket,
                        const int* __restrict__ gcur,
                        int* __restrict__ cnt, float* __restrict__ dinv,
                        unsigned short* __restrict__ ellu,
                        const unsigned int* __restrict__ Yb,  // [N][32] u32 view
                        unsigned int* __restrict__ Z,         // [N][32] u32 view
                        int N) {
    __shared__ unsigned short ellb[NPB * ELLW];  // 16 KB
    __shared__ int lcnt[NPB];
    __shared__ float sdinv[NPB];
    const int t = threadIdx.x;
    const int j = blockIdx.x;
    if (t < NPB) lcnt[t] = 0;
    {
        u32x4* eb4 = (u32x4*)ellb;
        u32x4 z = {0, 0, 0, 0};
        for (int i = t; i < NPB * ELLW / 8; i += 256) eb4[i] = z;
    }
    __syncthreads();
    int total = gcur[j];
    if (total > BCAP) total = BCAP;
    const unsigned int* bb = bucket + (size_t)j * BCAP;
    for (int i = t; i < total; i += 256) {
        unsigned int v = __builtin_nontemporal_load(bb + i);
        int ld = (v >> 16) & 127;
        int s = v & 0xffffu;
        int r = atomicAdd(&lcnt[ld], 1);
        if (r < ELLW) ellb[(ld << 6) + r] = (unsigned short)s;
    }
    __syncthreads();
    const int node0 = j << 7;
    if (t < NPB) {
        int node = node0 + t;
        int c = lcnt[t];
        float dv = rsqrtf((float)(c + 1));  // +1 = self loop
        sdinv[t] = dv;
        if (node < N) {
            cnt[node] = c > ELLW ? ELLW : c;
            dinv[node] = dv;
        }
    }
    __syncthreads();
    // dump ELL slab (u32x4 = 8 entries), rows 128B each
    u32x4* ellg = (u32x4*)ellu;
    const u32x4* eb = (const u32x4*)ellb;
    for (int i = t; i < NPB * (ELLW / 8); i += 256) {
        int node = node0 + (i >> 3);
        if (node < N) ellg[(size_t)node0 * 8 + i] = eb[i];
    }
    // Z = dinv .* Y (u32 = 2 bf16 feats per word)
    for (int w = t; w < NPB * 32; w += 256) {
        int nl = w >> 5, l = w & 31;
        int node = node0 + nl;
        if (node < N) {
            float dv = sdinv[nl];
            unsigned int y = Yb[(size_t)node * 32 + l];
            Z[(size_t)node * 32 + l] = pack2bf(dv * bf2f(y), dv * bf2f_hi(y));
        }
    }
}

// ---------- hop: 32-lane node-groups, lane = feature pair (u32 = 2 bf16) ----
// Zout[d] = dinv_d^2 * (Z[d] + sum_s Z[s]);  last hop: out = dinv_d*(...) + b.
__launch_bounds__(256)
__global__ void k_hop(const unsigned int* __restrict__ Zin,  // [N][32] u32
                      const unsigned short* __restrict__ ellu,
                      const int* __restrict__ cnt, const float* __restrict__ dinv,
                      unsigned int* __restrict__ Zout,       // hops 1-2
                      float* __restrict__ outf,              // last hop [N][64] fp32
                      const float* __restrict__ bc, int N) {
    int node = blockIdx.x * 8 + (threadIdx.x >> 5);
    if (node >= N) return;
    const int l = threadIdx.x & 31;
    const int deg = cnt[node];   // clamped <= 64 by k_build
    const float dn = dinv[node];
    unsigned int zself = Zin[(size_t)node * 32 + l];
    float a0 = bf2f(zself), a1 = 0.f, a2 = 0.f, a3 = 0.f;       // lo chains
    float b0 = bf2f_hi(zself), b1 = 0.f, b2 = 0.f, b3 = 0.f;    // hi chains
    const unsigned short* erow = ellu + (size_t)node * ELLW;
    int e = 0;
    for (; e + 16 <= deg; e += 16) {
        u32x4 ua = *(const u32x4*)(erow + e);      // 8 edges (broadcast 16B)
        u32x4 ub = *(const u32x4*)(erow + e + 8);  // 8 edges
        int s[16];
#pragma unroll
        for (int i = 0; i < 4; ++i) {
            s[2 * i]     = (int)(ua[i] & 0xffffu);
            s[2 * i + 1] = (int)(ua[i] >> 16);
            s[2 * i + 8] = (int)(ub[i] & 0xffffu);
            s[2 * i + 9] = (int)(ub[i] >> 16);
        }
        unsigned int z[16];
#pragma unroll
        for (int i = 0; i < 16; ++i) z[i] = Zin[(size_t)s[i] * 32 + l];
#pragma unroll
        for (int i = 0; i < 16; i += 4) {
            a0 += bf2f(z[i]);     b0 += bf2f_hi(z[i]);
            a1 += bf2f(z[i + 1]); b1 += bf2f_hi(z[i + 1]);
            a2 += bf2f(z[i + 2]); b2 += bf2f_hi(z[i + 2]);
            a3 += bf2f(z[i + 3]); b3 += bf2f_hi(z[i + 3]);
        }
    }
    if (e < deg) {  // guarded tail batch; ELL tail is zeroed -> s=0 reads safe
        u32x4 ua = *(const u32x4*)(erow + e);
        u32x4 ub = *(const u32x4*)(erow + e + 8);
        int s[16];
#pragma unroll
        for (int i = 0; i < 4; ++i) {
            s[2 * i]     = (int)(ua[i] & 0xffffu);
            s[2 * i + 1] = (int)(ua[i] >> 16);
            s[2 * i + 8] = (int)(ub[i] & 0xffffu);
            s[2 * i + 9] = (int)(ub[i] >> 16);
        }
        unsigned int z[16];
#pragma unroll
        for (int i = 0; i < 16; ++i) z[i] = Zin[(size_t)s[i] * 32 + l];
#pragma unroll
        for (int i = 0; i < 16; i += 4) {
            bool g0 = (e + i < deg), g1 = (e + i + 1 < deg);
            bool g2 = (e + i + 2 < deg), g3 = (e + i + 3 < deg);
            a0 += g0 ? bf2f(z[i]) : 0.f;     b0 += g0 ? bf2f_hi(z[i]) : 0.f;
            a1 += g1 ? bf2f(z[i + 1]) : 0.f; b1 += g1 ? bf2f_hi(z[i + 1]) : 0.f;
            a2 += g2 ? bf2f(z[i + 2]) : 0.f; b2 += g2 ? bf2f_hi(z[i + 2]) : 0.f;
            a3 += g3 ? bf2f(z[i + 3]) : 0.f; b3 += g3 ? bf2f_hi(z[i + 3]) : 0.f;
        }
    }
    float lo = (a0 + a1) + (a2 + a3);
    float hi = (b0 + b1) + (b2 + b3);
    if (outf) {
        float2 bv = *(const float2*)(bc + 2 * l);
        float2 o = make_float2(dn * lo + bv.x, dn * hi + bv.y);
        *(float2*)(outf + (size_t)node * NCLS + 2 * l) = o;
    } else {
        float d2 = dn * dn;
        Zout[(size_t)node * 32 + l] = pack2bf(d2 * lo, d2 * hi);
    }
}

extern "C" void kernel_launch(void* const* d_in, const int* in_sizes, int n_in,
                              void* d_out, int out_size, void* d_ws, size_t ws_size,
                              hipStream_t stream) {
    const void* X  = d_in[0];
    const void* EI = d_in[1];
    const void* W  = d_in[2];
    const void* B  = d_in[3];
    float* out = (float*)d_out;

    const int N = in_sizes[0] / NFEAT;  // 50000
    const int twoE = in_sizes[1];       // 1,600,000
    const int E = twoE / 2;             // 800,000
    const int NB = (N + NPB - 1) / NPB; // 391 buckets

    // ---- carve workspace (256B aligned) ----
    char* p = (char*)d_ws;
    auto alloc = [&](size_t bytes) -> char* {
        char* q = p;
        p += (bytes + 255) & ~(size_t)255;
        return q;
    };
    int*   flag   = (int*)alloc(4);
    int*   fflag  = (int*)alloc(4);
    int*   gcur   = (int*)alloc((size_t)NB * 4);
    int*   cnt    = (int*)alloc((size_t)N * 4);
    float* dinv   = (float*)alloc((size_t)N * 4);
    unsigned short* Wt = (unsigned short*)alloc((size_t)NFEAT * NCLS * 2);
    float* bc     = (float*)alloc((size_t)NCLS * 4);
    unsigned int* bucket = (unsigned int*)alloc((size_t)NB * BCAP * 4);   // 6.4 MB
    unsigned short* ellu = (unsigned short*)alloc((size_t)N * ELLW * 2);  // 6.4 MB
    unsigned short* Y0 = (unsigned short*)alloc((size_t)N * NCLS * 2);    // 6.4 MB
    unsigned short* Z0 = (unsigned short*)alloc((size_t)N * NCLS * 2);    // 6.4 MB
    unsigned short* Z1 = (unsigned short*)alloc((size_t)N * NCLS * 2);    // 6.4 MB

    k_setup<<<2 + NFEAT * NCLS / 256, 256, 0, stream>>>(
        EI, twoE, N, (const unsigned int*)X, in_sizes[0] / 2,
        W, B, flag, fflag, gcur, NB, Wt, bc);

    const int ngemm = (N + 63) / 64;              // 782
    const int npart = (E + PCHUNK - 1) / PCHUNK;  // 98
    k_fused<<<ngemm + npart, 256, 0, stream>>>(X, Wt, Y0, N, NB, fflag,
                                               EI, E, flag, bucket, gcur, ngemm);

    k_build<<<NB, 256, 0, stream>>>(bucket, gcur, cnt, dinv, ellu,
                                    (const unsigned int*)Y0, (unsigned int*)Z0, N);

    const int nb_h = (N + 7) / 8;  // 6250
    k_hop<<<nb_h, 256, 0, stream>>>((const unsigned int*)Z0, ellu, cnt, dinv,
                                    (unsigned int*)Z1, nullptr, bc, N);
    k_hop<<<nb_h, 256, 0, stream>>>((const unsigned int*)Z1, ellu, cnt, dinv,
                                    (unsigned int*)Z0, nullptr, bc, N);
    k_hop<<<nb_h, 256, 0, stream>>>((const unsigned int*)Z0, ellu, cnt, dinv,
                                    nullptr, out, bc, N);
}